// Round 7
// baseline (923.753 us; speedup 1.0000x reference)
//
#include <hip/hip_runtime.h>
#include <hip/hip_bf16.h>
#include <math.h>

#define B_ 512
#define KSTEPS 8

typedef __attribute__((ext_vector_type(8))) short bf16x8;
typedef __attribute__((ext_vector_type(4))) float f32x4;

#if __has_builtin(__builtin_amdgcn_global_load_lds)
#define HAVE_GLL 1
#else
#define HAVE_GLL 0
#endif

__device__ __forceinline__ float gelu_exact(float x) {
  return 0.5f * x * (1.0f + erff(x * 0.70710678118654752f));
}

__device__ __forceinline__ unsigned short f2b(float f) {
  union { float f; unsigned int u; } x; x.f = f;
  unsigned int u = x.u;
  unsigned int r = (u + 0x7FFFu + ((u >> 16) & 1u)) >> 16;
  return (unsigned short)r;
}

__device__ __forceinline__ float blockReduceSum256(float v, float* red) {
  int t = threadIdx.x;
  red[t] = v; __syncthreads();
  #pragma unroll
  for (int st = 128; st > 0; st >>= 1) {
    if (t < st) red[t] += red[t + st];
    __syncthreads();
  }
  float r = red[0];
  __syncthreads();
  return r;
}

__device__ __forceinline__ float redu32(float v) {
  v += __shfl_xor(v, 1, 64); v += __shfl_xor(v, 2, 64); v += __shfl_xor(v, 4, 64);
  v += __shfl_xor(v, 8, 64); v += __shfl_xor(v, 16, 64);
  return v;
}

#if HAVE_GLL
__device__ __forceinline__ void load16_lds(const unsigned short* g, unsigned short* l) {
  __builtin_amdgcn_global_load_lds(
      (const __attribute__((address_space(1))) unsigned int*)g,
      (__attribute__((address_space(3))) unsigned int*)l, 16, 0, 0);
}
#define WAITV0 asm volatile("s_waitcnt vmcnt(0)" ::: "memory")
#define WAITV4 asm volatile("s_waitcnt vmcnt(4)" ::: "memory")
#define WAITV8 asm volatile("s_waitcnt vmcnt(8)" ::: "memory")
#define WAITV9 asm volatile("s_waitcnt vmcnt(9)" ::: "memory")
#else
__device__ __forceinline__ void load16_lds(const unsigned short* g, unsigned short* l) {
  bf16x8 v = *(const bf16x8*)g;
  *(bf16x8*)l = v;
}
#define WAITV0 asm volatile("s_waitcnt vmcnt(0) lgkmcnt(0)" ::: "memory")
#define WAITV4 asm volatile("s_waitcnt vmcnt(0) lgkmcnt(0)" ::: "memory")
#define WAITV8 asm volatile("s_waitcnt vmcnt(0) lgkmcnt(0)" ::: "memory")
#define WAITV9 asm volatile("s_waitcnt vmcnt(0) lgkmcnt(0)" ::: "memory")
#endif

#define BAR() { __builtin_amdgcn_s_barrier(); asm volatile("" ::: "memory"); }

// stage a [128 rows][128 k] bf16 tile (32 KB), swizzled: slot (r,c) holds src chunk c^(r&7)
__device__ __forceinline__ void stage_w128(const unsigned short* __restrict__ src,
                                           int rowstride, int row0s, int col0s,
                                           unsigned short* dst, int w, int l) {
  #pragma unroll
  for (int j = 0; j < 4; j++) {
    int rr = w * 4 + (l >> 4) + j * 32;
    int cs = (l & 15) ^ (rr & 7);
    load16_lds(src + (size_t)(row0s + rr) * rowstride + col0s + cs * 8,
               dst + j * 4096 + w * 512 + l * 8);
  }
}

// stage x slice [16 rows][128 cols] f32 (8 KB), linear
__device__ __forceinline__ void stage_x(const float* __restrict__ xg, int r0, int g,
                                        float* dst, int t) {
  load16_lds((const unsigned short*)(xg + (size_t)(r0 + (t >> 5)) * 2048 + g * 128 + (t & 31) * 4),
             (unsigned short*)(dst + (t >> 5) * 128 + (t & 31) * 4));
}

// 4 MFMA: A = [16][256] swizzled bf16 LDS, W-tile = [128][128] swizzled; K-half kh
__device__ __forceinline__ f32x4 mm_a16(const unsigned short* Abuf, const unsigned short* Wt,
                                        int kh, int w, int lr, int lk, f32x4 acc) {
  int rB = w * 16 + lr;
  #pragma unroll
  for (int m = 0; m < 4; m++) {
    int chA = kh * 16 + m * 4 + lk;
    bf16x8 af = *(const bf16x8*)&Abuf[lr * 256 + ((chA ^ (lr & 7)) << 3)];
    bf16x8 bf = *(const bf16x8*)&Wt[rB * 128 + (((m * 4 + lk) ^ (rB & 7)) << 3)];
    acc = __builtin_amdgcn_mfma_f32_16x16x32_bf16(af, bf, acc, 0, 0, 0);
  }
  return acc;
}

// 4 MFMA: A = y_tile [16][128] swizzled, W-tile = [128][128] swizzled (full K=128)
__device__ __forceinline__ f32x4 mm_yt(const unsigned short* yt, const unsigned short* Et,
                                       int w, int lr, int lk, f32x4 acc) {
  int rB = w * 16 + lr;
  #pragma unroll
  for (int m = 0; m < 4; m++) {
    bf16x8 af = *(const bf16x8*)&yt[lr * 128 + (((m * 4 + lk) ^ (lr & 7)) << 3)];
    bf16x8 bf = *(const bf16x8*)&Et[rB * 128 + (((m * 4 + lk) ^ (rB & 7)) << 3)];
    acc = __builtin_amdgcn_mfma_f32_16x16x32_bf16(af, bf, acc, 0, 0, 0);
  }
  return acc;
}

// ================= the fused thinking-loop kernel =================
// grid: 32 blocks x 512 threads; block owns rows r0..r0+15 end-to-end.
__global__ __launch_bounds__(512) void k_think(
    const unsigned short* __restrict__ h_bf,   // [512][256]
    const unsigned short* __restrict__ WxiT,   // [2048][256]
    const float* __restrict__ bias_x0,         // [2048]
    const float* __restrict__ bybx,            // [512][512] (b_y | b_x)
    const unsigned short* __restrict__ DyT,    // [2048][256]
    const unsigned short* __restrict__ DxT,    // [2048][256]
    const unsigned short* __restrict__ ET,     // [256][2048]
    const float* __restrict__ lna_g, const float* __restrict__ lna_b,
    const float* __restrict__ lnz_g, const float* __restrict__ lnz_b,
    const float* __restrict__ log_damp,
    const float* __restrict__ vh_w1, const float* __restrict__ vh_b1,
    const float* __restrict__ vh_w2, const float* __restrict__ vh_b2,
    float* __restrict__ xg,   // [512][2048]
    float* __restrict__ xwg,  // [7][512][2048]
    float* __restrict__ zhg,  // [7][512][256]
    float* __restrict__ outp)
{
  __shared__ __align__(16) unsigned short stg[2][32768];  // 2 x 64KB pair buffers
  __shared__ __align__(16) float xsl[2][2048];            // 2 x 8KB x-slices
  __shared__ __align__(16) unsigned short abuf[4096];     // acond / zbx / h  [16][256] swz
  __shared__ __align__(16) unsigned short ytile[2048];    // [16][128] swz
  __shared__ float dots[16][7][4];

  const int t = threadIdx.x;
  const int l = t & 63, w = t >> 6;
  const int lr = l & 15, lk = l >> 4;
  const int r0 = blockIdx.x * 16;
  const float lam = 1.f / (1.f + expf(-log_damp[0]));

  // ---------- prologue: stage h rows -> abuf ----------
  {
    int row = t >> 5, c = t & 31;
    int cs = c ^ (row & 7);
    load16_lds(h_bf + (size_t)(r0 + row) * 256 + cs * 8, abuf + row * 256 + c * 8);
  }
  __syncthreads();

  // ---------- x0 = relu(h @ Wxi + bias_x0): 16 pairs over WxiT ----------
  stage_w128(WxiT, 256, 0, 0, stg[0], w, l);
  stage_w128(WxiT, 256, 0, 128, stg[0] + 16384, w, l);
  stage_w128(WxiT, 256, 128, 0, stg[1], w, l);
  stage_w128(WxiT, 256, 128, 128, stg[1] + 16384, w, l);
  for (int p = 0; p < 16; p++) {
    if (p == 15) { WAITV0; } else { WAITV8; }
    BAR();
    const unsigned short* buf = stg[p & 1];
    f32x4 xacc = (f32x4){0.f, 0.f, 0.f, 0.f};
    xacc = mm_a16(abuf, buf, 0, w, lr, lk, xacc);
    xacc = mm_a16(abuf, buf + 16384, 1, w, lr, lk, xacc);
    int cg = p * 128 + w * 16 + lr;
    float bia = bias_x0[cg];
    #pragma unroll
    for (int q = 0; q < 4; q++)
      xg[(size_t)(r0 + lk * 4 + q) * 2048 + cg] = fmaxf(xacc[q] + bia, 0.f);
    BAR();
    if (p + 2 < 16) {
      stage_w128(WxiT, 256, (p + 2) * 128, 0, stg[p & 1], w, l);
      stage_w128(WxiT, 256, (p + 2) * 128, 128, stg[p & 1] + 16384, w, l);
    }
  }
  __syncthreads();

  // ---------- 8 thinking steps ----------
  for (int k = 0; k < KSTEPS; k++) {
    // ===== phase 1: step_a -> acond in abuf =====
    {
      const int row = t >> 5;
      const int l32 = t & 31;
      const int hh = l32 >> 3, sub = l32 & 7;
      if (k >= 1) {
        const float* xr = xg + (size_t)(r0 + row) * 2048 + hh * 512 + sub * 4;
        float4 xv[16];
        float nrm = 0.f;
        #pragma unroll
        for (int j2 = 0; j2 < 16; j2++) {
          xv[j2] = *(const float4*)(xr + j2 * 32);
          nrm += xv[j2].x * xv[j2].x + xv[j2].y * xv[j2].y +
                 xv[j2].z * xv[j2].z + xv[j2].w * xv[j2].w;
        }
        nrm += __shfl_xor(nrm, 1, 64); nrm += __shfl_xor(nrm, 2, 64); nrm += __shfl_xor(nrm, 4, 64);
        float inv = 1.f / (sqrtf(nrm) + 1e-8f);
        float* xwr = xwg + ((size_t)(k - 1) * B_ + r0 + row) * 2048 + hh * 512 + sub * 4;
        #pragma unroll
        for (int j2 = 0; j2 < 16; j2++) {
          float4 o; o.x = xv[j2].x * inv; o.y = xv[j2].y * inv;
          o.z = xv[j2].z * inv; o.w = xv[j2].w * inv;
          *(float4*)(xwr + j2 * 32) = o;
        }
        if (sub == 0) dots[row][k - 1][hh] = nrm * inv;
        for (int jj = 0; jj < k - 1; jj++) {
          const float* wr2 = xwg + ((size_t)jj * B_ + r0 + row) * 2048 + hh * 512 + sub * 4;
          float s = 0.f;
          #pragma unroll
          for (int j2 = 0; j2 < 16; j2++) {
            float4 wv = *(const float4*)(wr2 + j2 * 32);
            s += xv[j2].x * wv.x + xv[j2].y * wv.y + xv[j2].z * wv.z + xv[j2].w * wv.w;
          }
          s += __shfl_xor(s, 1, 64); s += __shfl_xor(s, 2, 64); s += __shfl_xor(s, 4, 64);
          if (sub == 0) dots[row][jj][hh] = s;
        }
      }
      __syncthreads();
      // a = sum_j coef_j * dots * zh[j]  (+ b_y), LN -> acond
      float a8[8] = {0.f, 0.f, 0.f, 0.f, 0.f, 0.f, 0.f, 0.f};
      {
        float lp = 1.f;
        const int hd = l32 >> 3;
        for (int jj = k - 1; jj >= 0; jj--) {
          float cj = (1.f - lam) * lp * dots[row][jj][hd];
          const float* zr = zhg + ((size_t)jj * B_ + r0 + row) * 256 + l32 * 8;
          float4 z0 = *(const float4*)zr, z1 = *(const float4*)(zr + 4);
          a8[0] += cj * z0.x; a8[1] += cj * z0.y; a8[2] += cj * z0.z; a8[3] += cj * z0.w;
          a8[4] += cj * z1.x; a8[5] += cj * z1.y; a8[6] += cj * z1.z; a8[7] += cj * z1.w;
          lp *= lam;
        }
      }
      const float* byr = bybx + (size_t)(r0 + row) * 512 + l32 * 8;
      float4 b0 = *(const float4*)byr, b1v = *(const float4*)(byr + 4);
      a8[0] += b0.x; a8[1] += b0.y; a8[2] += b0.z; a8[3] += b0.w;
      a8[4] += b1v.x; a8[5] += b1v.y; a8[6] += b1v.z; a8[7] += b1v.w;
      float s = a8[0] + a8[1] + a8[2] + a8[3] + a8[4] + a8[5] + a8[6] + a8[7];
      s = redu32(s);
      float mu = s * (1.f / 256.f);
      float s2 = 0.f;
      #pragma unroll
      for (int j2 = 0; j2 < 8; j2++) { float cc = a8[j2] - mu; s2 += cc * cc; }
      s2 = redu32(s2);
      float rin = rsqrtf(s2 * (1.f / 256.f) + 1e-5f);
      bf16x8 pk;
      #pragma unroll
      for (int j2 = 0; j2 < 8; j2++) {
        int d = l32 * 8 + j2;
        pk[j2] = (short)f2b((a8[j2] - mu) * rin * lna_g[d] + lna_b[d]);
      }
      *(bf16x8*)&abuf[row * 256 + ((l32 ^ (row & 7)) << 3)] = pk;
    }
    __syncthreads();

    // ===== phase 2: y = relu(acond@Dy)*x ; z = y@E (32 pairs: D,E per group) =====
    f32x4 zacc0 = (f32x4){0.f, 0.f, 0.f, 0.f};
    f32x4 zacc1 = (f32x4){0.f, 0.f, 0.f, 0.f};
    stage_w128(DyT, 256, 0, 0, stg[0], w, l);
    stage_w128(DyT, 256, 0, 128, stg[0] + 16384, w, l);
    stage_x(xg, r0, 0, xsl[0], t);
    stage_w128(ET, 2048, 0, 0, stg[1], w, l);
    stage_w128(ET, 2048, 128, 0, stg[1] + 16384, w, l);
    for (int p = 0; p < 32; p++) {
      if (p == 31) { WAITV0; } else if (p & 1) { WAITV9; } else { WAITV8; }
      BAR();
      const unsigned short* buf = stg[p & 1];
      int g = p >> 1;
      if (!(p & 1)) {
        f32x4 yacc = (f32x4){0.f, 0.f, 0.f, 0.f};
        yacc = mm_a16(abuf, buf, 0, w, lr, lk, yacc);
        yacc = mm_a16(abuf, buf + 16384, 1, w, lr, lk, yacc);
        #pragma unroll
        for (int q = 0; q < 4; q++) {
          int rr = lk * 4 + q, cl = w * 16 + lr;
          float v = fmaxf(yacc[q], 0.f) * xsl[g & 1][rr * 128 + cl];
          ytile[rr * 128 + ((((cl >> 3) ^ (rr & 7)) << 3) | (cl & 7))] = f2b(v);
        }
      } else {
        zacc0 = mm_yt(ytile, buf, w, lr, lk, zacc0);
        zacc1 = mm_yt(ytile, buf + 16384, w, lr, lk, zacc1);
      }
      BAR();
      if (p + 2 < 32) {
        int g2 = (p + 2) >> 1;
        if (!((p + 2) & 1)) {
          stage_w128(DyT, 256, g2 * 128, 0, stg[p & 1], w, l);
          stage_w128(DyT, 256, g2 * 128, 128, stg[p & 1] + 16384, w, l);
          stage_x(xg, r0, g2, xsl[g2 & 1], t);
        } else {
          stage_w128(ET, 2048, 0, g2 * 128, stg[p & 1], w, l);
          stage_w128(ET, 2048, 128, g2 * 128, stg[p & 1] + 16384, w, l);
        }
      }
    }
    __syncthreads();

    // ===== phase 3: LN(z) -> zh / zbx (or value-head input) =====
    float* zt = (float*)&stg[0][0];   // [16][256] f32
    #pragma unroll
    for (int q = 0; q < 4; q++) {
      zt[(lk * 4 + q) * 256 + w * 16 + lr] = zacc0[q];
      zt[(lk * 4 + q) * 256 + 128 + w * 16 + lr] = zacc1[q];
    }
    __syncthreads();
    {
      int row = t >> 5, c = t & 31;
      float zv[8]; float s = 0.f;
      #pragma unroll
      for (int j2 = 0; j2 < 8; j2++) { zv[j2] = zt[row * 256 + c * 8 + j2]; s += zv[j2]; }
      s = redu32(s);
      float mu = s * (1.f / 256.f);
      float s2 = 0.f;
      #pragma unroll
      for (int j2 = 0; j2 < 8; j2++) { float cc = zv[j2] - mu; s2 += cc * cc; }
      s2 = redu32(s2);
      float rin = rsqrtf(s2 * (1.f / 256.f) + 1e-5f);
      float vn[8];
      #pragma unroll
      for (int j2 = 0; j2 < 8; j2++) {
        int d = c * 8 + j2;
        vn[j2] = (zv[j2] - mu) * rin * lnz_g[d] + lnz_b[d];
      }
      if (k < KSTEPS - 1) {
        float* zr = zhg + ((size_t)k * B_ + r0 + row) * 256 + c * 8;
        float4 o0, o1;
        o0.x = vn[0]; o0.y = vn[1]; o0.z = vn[2]; o0.w = vn[3];
        o1.x = vn[4]; o1.y = vn[5]; o1.z = vn[6]; o1.w = vn[7];
        *(float4*)zr = o0; *(float4*)(zr + 4) = o1;
        const float* bxr = bybx + (size_t)(r0 + row) * 512 + 256 + c * 8;
        bf16x8 pk;
        #pragma unroll
        for (int j2 = 0; j2 < 8; j2++) pk[j2] = (short)f2b(vn[j2] + bxr[j2]);
        *(bf16x8*)&abuf[row * 256 + ((c ^ (row & 7)) << 3)] = pk;
      } else {
        #pragma unroll
        for (int j2 = 0; j2 < 8; j2++) zt[row * 256 + c * 8 + j2] = vn[j2];
      }
    }
    __syncthreads();

    if (k < KSTEPS - 1) {
      // ===== phase 4: x += relu(zbx @ Dx): 16 pairs =====
      stage_w128(DxT, 256, 0, 0, stg[0], w, l);
      stage_w128(DxT, 256, 0, 128, stg[0] + 16384, w, l);
      stage_x(xg, r0, 0, xsl[0], t);
      stage_w128(DxT, 256, 128, 0, stg[1], w, l);
      stage_w128(DxT, 256, 128, 128, stg[1] + 16384, w, l);
      stage_x(xg, r0, 1, xsl[1], t);
      for (int p = 0; p < 16; p++) {
        if (p == 15) { WAITV0; } else { WAITV9; }
        BAR();
        const unsigned short* buf = stg[p & 1];
        f32x4 xacc = (f32x4){0.f, 0.f, 0.f, 0.f};
        xacc = mm_a16(abuf, buf, 0, w, lr, lk, xacc);
        xacc = mm_a16(abuf, buf + 16384, 1, w, lr, lk, xacc);
        int cg = p * 128 + w * 16 + lr;
        #pragma unroll
        for (int q = 0; q < 4; q++) {
          int rr = lk * 4 + q;
          xg[(size_t)(r0 + rr) * 2048 + cg] =
              xsl[p & 1][rr * 128 + w * 16 + lr] + fmaxf(xacc[q], 0.f);
        }
        BAR();
        if (p + 2 < 16) {
          stage_w128(DxT, 256, (p + 2) * 128, 0, stg[p & 1], w, l);
          stage_w128(DxT, 256, (p + 2) * 128, 128, stg[p & 1] + 16384, w, l);
          stage_x(xg, r0, p + 2, xsl[p & 1], t);
        }
      }
      __syncthreads();
    } else {
      // ===== value head: v = tanh(gelu(z@W1+b1)@w2 + b2) =====
      int row = t >> 5, c = t & 31;
      float a0 = 0.f, a1 = 0.f, a2 = 0.f, a3 = 0.f;
      for (int d = 0; d < 256; d++) {
        float zd = zt[row * 256 + d];
        float4 wv = *(const float4*)&vh_w1[(size_t)d * 128 + c * 4];
        a0 += zd * wv.x; a1 += zd * wv.y; a2 += zd * wv.z; a3 += zd * wv.w;
      }
      float sj = gelu_exact(a0 + vh_b1[c * 4 + 0]) * vh_w2[c * 4 + 0]
               + gelu_exact(a1 + vh_b1[c * 4 + 1]) * vh_w2[c * 4 + 1]
               + gelu_exact(a2 + vh_b1[c * 4 + 2]) * vh_w2[c * 4 + 2]
               + gelu_exact(a3 + vh_b1[c * 4 + 3]) * vh_w2[c * 4 + 3];
      sj = redu32(sj);
      if (c == 0) outp[r0 + row] = tanhf(sj + vh_b2[0]);
    }
  }
}

// ================= encoder-side kernels =================

// f32 64x64-tile GEMM. ACT: 0 none, 2 gelu. Split-K raw partials when gridDim.z>1.
template<int ACT>
__global__ __launch_bounds__(256) void gemm_tile(
    const float* __restrict__ A, const float* __restrict__ W,
    const float* __restrict__ bias, float* __restrict__ out,
    unsigned short* __restrict__ outb, int M, int N, int K, int kchunk)
{
  __shared__ float As[16][68];
  __shared__ float Bs[16][68];
  const int tid = threadIdx.x;
  const int row0 = blockIdx.y * 64;
  const int col0 = blockIdx.x * 64;
  const int k0 = blockIdx.z * kchunk;
  const int ty = tid >> 4, tx = tid & 15;
  const int ar = tid >> 4, ak = tid & 15;
  const int br = tid >> 6, bc = tid & 63;
  float acc[4][4] = {};
  for (int kk = k0; kk < k0 + kchunk; kk += 16) {
    #pragma unroll
    for (int i = 0; i < 4; i++) {
      int r = ar + i * 16;
      As[ak][r] = A[(size_t)(row0 + r) * K + kk + ak];
    }
    #pragma unroll
    for (int i = 0; i < 4; i++) {
      int kr = br + i * 4;
      Bs[kr][bc] = W[(size_t)(kk + kr) * N + col0 + bc];
    }
    __syncthreads();
    #pragma unroll
    for (int q = 0; q < 16; q++) {
      float4 av = *(const float4*)&As[q][ty * 4];
      float4 bv = *(const float4*)&Bs[q][tx * 4];
      float aa[4] = {av.x, av.y, av.z, av.w};
      float bb[4] = {bv.x, bv.y, bv.z, bv.w};
      #pragma unroll
      for (int i = 0; i < 4; i++)
        #pragma unroll
        for (int j = 0; j < 4; j++)
          acc[i][j] = fmaf(aa[i], bb[j], acc[i][j]);
    }
    __syncthreads();
  }
  const bool parts = (gridDim.z > 1);
  float* o = out + (parts ? (size_t)blockIdx.z * (size_t)M * N : (size_t)0);
  #pragma unroll
  for (int i = 0; i < 4; i++) {
    int r = row0 + ty * 4 + i;
    #pragma unroll
    for (int j = 0; j < 4; j++) {
      int c = col0 + tx * 4 + j;
      float v = acc[i][j];
      if (!parts) {
        if (bias) v += bias[c];
        if (ACT == 2) v = gelu_exact(v);
      }
      o[(size_t)r * N + c] = v;
      if (!parts && outb) outb[(size_t)r * N + c] = f2b(v);
    }
  }
}

// Wyx = enc_w2 @ [By|Bx]  (f32 [256][512]); Wxi = enc_w2 @ xinit_w (f32 [256][2048]);
// bias_comb[n] = b2 @ sel[:,n] (+ xinit_b for n>=512)
__global__ __launch_bounds__(256) void k_wcomb(
    const float* __restrict__ enc_w2, const float* __restrict__ By_w,
    const float* __restrict__ Bx_w, const float* __restrict__ xinit_w,
    const float* __restrict__ b2, const float* __restrict__ xinit_b,
    float* __restrict__ Wyx, float* __restrict__ Wxi, float* __restrict__ bias_comb)
{
  const int tid = threadIdx.x;
  if (blockIdx.y == 4) {
    int col = blockIdx.x * 64 + (tid >> 2);
    int part = tid & 3;
    float s = 0.f;
    for (int m = part * 64; m < part * 64 + 64; m++) {
      float wv = col < 256 ? By_w[(size_t)m * 256 + col]
               : col < 512 ? Bx_w[(size_t)m * 256 + col - 256]
                           : xinit_w[(size_t)m * 2048 + col - 512];
      s += b2[m] * wv;
    }
    s += __shfl_xor(s, 1, 64); s += __shfl_xor(s, 2, 64);
    if (part == 0) bias_comb[col] = s + (col >= 512 ? xinit_b[col - 512] : 0.f);
    return;
  }
  __shared__ float As[16][68];
  __shared__ float Bs[16][68];
  const int row0 = blockIdx.y * 64;
  const int col0 = blockIdx.x * 64;
  const int ty = tid >> 4, tx = tid & 15;
  const int ar = tid >> 4, ak = tid & 15;
  const int br = tid >> 6, bc = tid & 63;
  float acc[4][4] = {};
  for (int kk = 0; kk < 256; kk += 16) {
    #pragma unroll
    for (int i = 0; i < 4; i++) {
      int r = ar + i * 16;
      As[ak][r] = enc_w2[(size_t)(row0 + r) * 256 + kk + ak];
    }
    #pragma unroll
    for (int i = 0; i < 4; i++) {
      int kr = br + i * 4;
      int ncol = col0 + bc;
      float wv = ncol < 256 ? By_w[(size_t)(kk + kr) * 256 + ncol]
               : ncol < 512 ? Bx_w[(size_t)(kk + kr) * 256 + ncol - 256]
                            : xinit_w[(size_t)(kk + kr) * 2048 + ncol - 512];
      Bs[kr][bc] = wv;
    }
    __syncthreads();
    #pragma unroll
    for (int q = 0; q < 16; q++) {
      float4 av = *(const float4*)&As[q][ty * 4];
      float4 bv = *(const float4*)&Bs[q][tx * 4];
      float aa[4] = {av.x, av.y, av.z, av.w};
      float bb[4] = {bv.x, bv.y, bv.z, bv.w};
      #pragma unroll
      for (int i = 0; i < 4; i++)
        #pragma unroll
        for (int j = 0; j < 4; j++)
          acc[i][j] = fmaf(aa[i], bb[j], acc[i][j]);
    }
    __syncthreads();
  }
  #pragma unroll
  for (int i = 0; i < 4; i++) {
    int r = row0 + ty * 4 + i;
    #pragma unroll
    for (int j = 0; j < 4; j++) {
      int c = col0 + tx * 4 + j;
      if (c < 512) Wyx[(size_t)r * 512 + c] = acc[i][j];
      else         Wxi[(size_t)r * 2048 + c - 512] = acc[i][j];
    }
  }
}

// transposes -> bf16 [N][K] layouts
__global__ __launch_bounds__(256) void k_prep(
    const float* __restrict__ D_y, const float* __restrict__ D_x,
    const float* __restrict__ Wxi, const float* __restrict__ E,
    unsigned short* __restrict__ DyT, unsigned short* __restrict__ DxT,
    unsigned short* __restrict__ WxiT, unsigned short* __restrict__ ET)
{
  __shared__ float T[64][65];
  const int t = threadIdx.x;
  const float* in; unsigned short* out; int Kd, instride, head, nx;
  switch (blockIdx.y) {
    case 0:  in = D_y; out = DyT;  Kd = 256;  instride = 2048; head = 1; nx = 32; break;
    case 1:  in = D_x; out = DxT;  Kd = 256;  instride = 2048; head = 1; nx = 32; break;
    case 2:  in = Wxi; out = WxiT; Kd = 256;  instride = 2048; head = 0; nx = 32; break;
    default: in = E;   out = ET;   Kd = 2048; instride = 256;  head = 0; nx = 4;  break;
  }
  const int n0 = ((int)blockIdx.x % nx) * 64, k0 = ((int)blockIdx.x / nx) * 64;
  const int tx = t & 63, ty = t >> 6;
  #pragma unroll
  for (int i = 0; i < 16; i++) {
    int k = k0 + ty + i * 4;
    int n = n0 + tx;
    float v;
    if (head) v = in[((size_t)(n >> 9) * 256 + k) * 512 + (n & 511)];
    else      v = in[(size_t)k * instride + n];
    T[ty + i * 4][tx] = v;
  }
  __syncthreads();
  #pragma unroll
  for (int i = 0; i < 16; i++) {
    int n = n0 + ty + i * 4;
    out[(size_t)n * Kd + k0 + tx] = f2b(T[tx][ty + i * 4]);
  }
}

// h = LN(gelu(sum parts + b1)); also bf16 copy
__global__ __launch_bounds__(256) void k_ln_enc(
    const float* __restrict__ in, int nparts, int stride,
    const float* __restrict__ pre_bias,
    const float* __restrict__ g, const float* __restrict__ bta,
    float* __restrict__ out, unsigned short* __restrict__ out_bf)
{
  __shared__ float red[256];
  int b = blockIdx.x, d = threadIdx.x;
  float v = 0.f;
  for (int p = 0; p < nparts; p++) v += in[(size_t)p * stride + (size_t)b * 256 + d];
  v = gelu_exact(v + pre_bias[d]);
  float mu = blockReduceSum256(v, red) * (1.f / 256.f);
  float c = v - mu;
  float var = blockReduceSum256(c * c, red) * (1.f / 256.f);
  float vn = c * rsqrtf(var + 1e-5f) * g[d] + bta[d];
  out[(size_t)b * 256 + d] = vn;
  out_bf[(size_t)b * 256 + d] = f2b(vn);
}

extern "C" void kernel_launch(void* const* d_in, const int* in_sizes, int n_in,
                              void* d_out, int out_size, void* d_ws, size_t ws_size,
                              hipStream_t stream) {
  const float* boards   = (const float*)d_in[0];
  const float* enc_w1   = (const float*)d_in[1];
  const float* enc_b1   = (const float*)d_in[2];
  const float* enc_ln_g = (const float*)d_in[3];
  const float* enc_ln_b = (const float*)d_in[4];
  const float* enc_w2   = (const float*)d_in[5];
  const float* enc_b2   = (const float*)d_in[6];
  const float* xinit_w  = (const float*)d_in[7];
  const float* xinit_b  = (const float*)d_in[8];
  const float* D_y      = (const float*)d_in[9];
  const float* E        = (const float*)d_in[10];
  const float* D_x      = (const float*)d_in[11];
  const float* By_w     = (const float*)d_in[12];
  const float* Bx_w     = (const float*)d_in[13];
  const float* lna_g    = (const float*)d_in[14];
  const float* lna_b    = (const float*)d_in[15];
  const float* lnz_g    = (const float*)d_in[16];
  const float* lnz_b    = (const float*)d_in[17];
  const float* log_damp = (const float*)d_in[18];
  const float* vh_w1    = (const float*)d_in[19];
  const float* vh_b1    = (const float*)d_in[20];
  const float* vh_w2    = (const float*)d_in[21];
  const float* vh_b2    = (const float*)d_in[22];
  float* outp = (float*)d_out;

  float* ws = (float*)d_ws;
  size_t o = 0;
  float* x        = ws + o; o += (size_t)512 * 2048;
  float* xw       = ws + o; o += (size_t)7 * 512 * 2048;
  float* zh       = ws + o; o += (size_t)7 * 512 * 256;
  float* hparts   = ws + o; o += (size_t)8 * 512 * 256;
  float* h        = ws + o; o += (size_t)512 * 256;
  float* bybx     = ws + o; o += (size_t)512 * 512;
  float* Wyx      = ws + o; o += (size_t)256 * 512;
  float* Wxi      = ws + o; o += (size_t)256 * 2048;
  float* bias_comb= ws + o; o += 2560;
  unsigned short* h_bf = (unsigned short*)(ws + o); o += (size_t)512 * 256 / 2;
  unsigned short* DyT  = (unsigned short*)(ws + o); o += (size_t)2048 * 256 / 2;
  unsigned short* DxT  = (unsigned short*)(ws + o); o += (size_t)2048 * 256 / 2;
  unsigned short* ET   = (unsigned short*)(ws + o); o += (size_t)256 * 2048 / 2;
  unsigned short* WxiT = (unsigned short*)(ws + o); o += (size_t)2048 * 256 / 2;

  // 1. combined weights + biases
  k_wcomb<<<dim3(40, 5), 256, 0, stream>>>(enc_w2, By_w, Bx_w, xinit_w,
                                           enc_b2, xinit_b, Wyx, Wxi, bias_comb);
  // 2. bf16 transposed weights
  k_prep<<<dim3(128, 4), 256, 0, stream>>>(D_y, D_x, Wxi, E, DyT, DxT, WxiT, ET);
  // 3. enc1: boards @ enc_w1 (split-K 8)
  gemm_tile<0><<<dim3(4, 8, 8), 256, 0, stream>>>(boards, enc_w1, nullptr, hparts,
                                                  nullptr, 512, 256, 768, 96);
  // 4. h = LN(gelu(. + b1))  (+ bf16 copy)
  k_ln_enc<<<512, 256, 0, stream>>>(hparts, 8, 512 * 256, enc_b1,
                                    enc_ln_g, enc_ln_b, h, h_bf);
  // 5. [b_y | b_x] = h @ Wyx + bias
  gemm_tile<0><<<dim3(8, 8, 1), 256, 0, stream>>>(h, Wyx, bias_comb, bybx, nullptr,
                                                  512, 512, 256, 256);
  // 6. fused loop: x0, 8 steps, value head
  k_think<<<32, 512, 0, stream>>>(h_bf, WxiT, bias_comb + 512, bybx, DyT, DxT, ET,
                                  lna_g, lna_b, lnz_g, lnz_b, log_damp,
                                  vh_w1, vh_b1, vh_w2, vh_b2,
                                  x, xw, zh, outp);
}

// Round 8
// 433.187 us; speedup vs baseline: 2.1325x; 2.1325x over previous
//
#include <hip/hip_runtime.h>
#include <hip/hip_bf16.h>
#include <math.h>

#define B_ 512
#define D_ 256
#define NTOT_ 2048
#define KSTEPS 8

typedef __attribute__((ext_vector_type(8))) short bf16x8;
typedef __attribute__((ext_vector_type(4))) float f32x4;

#if __has_builtin(__builtin_amdgcn_global_load_lds)
#define HAVE_GLL 1
#else
#define HAVE_GLL 0
#endif

__device__ __forceinline__ float gelu_exact(float x) {
  return 0.5f * x * (1.0f + erff(x * 0.70710678118654752f));
}

__device__ __forceinline__ unsigned short f2b(float f) {
  union { float f; unsigned int u; } x; x.f = f;
  unsigned int u = x.u;
  unsigned int r = (u + 0x7FFFu + ((u >> 16) & 1u)) >> 16;
  return (unsigned short)r;
}

__device__ __forceinline__ float blockReduceSum256(float v, float* red) {
  int t = threadIdx.x;
  red[t] = v; __syncthreads();
  #pragma unroll
  for (int st = 128; st > 0; st >>= 1) {
    if (t < st) red[t] += red[t + st];
    __syncthreads();
  }
  float r = red[0];
  __syncthreads();
  return r;
}

__device__ __forceinline__ float red8(float v) {  // sum over 8-lane group
  v += __shfl_xor(v, 1, 64); v += __shfl_xor(v, 2, 64); v += __shfl_xor(v, 4, 64);
  return v;
}

// stage16: GLL fans out lane*16B automatically from wave-uniform base.
#if HAVE_GLL
__device__ __forceinline__ void stage16(const unsigned short* g, unsigned short* base, int lane) {
  (void)lane;
  __builtin_amdgcn_global_load_lds(
      (const __attribute__((address_space(1))) unsigned int*)g,
      (__attribute__((address_space(3))) unsigned int*)base, 16, 0, 0);
}
#define WAITV0 asm volatile("s_waitcnt vmcnt(0)" ::: "memory")
#else
__device__ __forceinline__ void stage16(const unsigned short* g, unsigned short* base, int lane) {
  *(bf16x8*)(base + lane * 8) = *(const bf16x8*)g;
}
#define WAITV0 asm volatile("s_waitcnt vmcnt(0) lgkmcnt(0)" ::: "memory")
#endif

#define BAR() { __builtin_amdgcn_s_barrier(); asm volatile("" ::: "memory"); }

// ---------------- x-GEMM: 64x64 tile, K=256, N=2048, 512 threads ----------------
// EPI 0: xio = relu(A@W^T + bias)   (x0 init)
// EPI 1: xio += relu(A@W^T)
// DOTS: post-phase accumulates norm^2(x_new) and dot(xw_j, x_new), j<k,
//       into parity buffers p = k&1 (atomicAdd per (row, head)).
template<int EPI, int DOTS>
__global__ __launch_bounds__(512) void k_gemm_x(
    const unsigned short* __restrict__ A, const unsigned short* __restrict__ W,
    const float* __restrict__ bias, float* __restrict__ xio,
    const float* __restrict__ xw, float* __restrict__ dotbuf,
    float* __restrict__ normbuf, int k)
{
  __shared__ __align__(16) unsigned short As[2 * 4096];
  __shared__ __align__(16) unsigned short Ws[2 * 4096];
  const int t = threadIdx.x;
  const int lane = t & 63, w = t >> 6;
  const int lr = lane & 15, lk = lane >> 4;
  const int l3 = lane >> 3, cch = lane & 7;
  const int n0 = blockIdx.x * 64, m0 = blockIdx.y * 64;
  const int wm = w & 3, wn = w >> 2;

  f32x4 acc[2];
  acc[0] = (f32x4){0.f, 0.f, 0.f, 0.f};
  acc[1] = (f32x4){0.f, 0.f, 0.f, 0.f};

  #define STGX(tt) {                                                              \
      int buf_ = (tt) & 1; int kk_ = (tt) * 64;                                   \
      int r_ = w * 8 + l3;                                                        \
      stage16(&A[(size_t)(m0 + r_) * 256 + kk_ + ((cch ^ (r_ & 7)) << 3)],        \
              &As[buf_ * 4096 + w * 512], lane);                                  \
      stage16(&W[(size_t)(n0 + r_) * 256 + kk_ + ((cch ^ (r_ & 7)) << 3)],        \
              &Ws[buf_ * 4096 + w * 512], lane); }
  STGX(0);
  for (int tt = 0; tt < 4; tt++) {
    WAITV0;
    BAR();
    if (tt + 1 < 4) STGX(tt + 1);
    const unsigned short* Ab = &As[(tt & 1) * 4096];
    const unsigned short* Wb = &Ws[(tt & 1) * 4096];
    #pragma unroll
    for (int ks = 0; ks < 2; ks++) {
      int q = ks * 4 + lk;
      int r = wm * 16 + lr;
      bf16x8 af = *(const bf16x8*)&Ab[r * 64 + ((q ^ (r & 7)) << 3)];
      #pragma unroll
      for (int j = 0; j < 2; j++) {
        int c = wn * 32 + j * 16 + lr;
        bf16x8 bf = *(const bf16x8*)&Wb[c * 64 + ((q ^ (c & 7)) << 3)];
        acc[j] = __builtin_amdgcn_mfma_f32_16x16x32_bf16(af, bf, acc[j], 0, 0, 0);
      }
    }
    BAR();
  }
  #undef STGX

  float vout[2][4];
  #pragma unroll
  for (int j = 0; j < 2; j++)
    #pragma unroll
    for (int qq = 0; qq < 4; qq++) {
      int r = m0 + wm * 16 + lk * 4 + qq;
      int c = n0 + wn * 32 + j * 16 + lr;
      float v = acc[j][qq];
      if (EPI == 0) v = fmaxf(v + bias[c], 0.f);
      else          v = fmaxf(v, 0.f) + xio[(size_t)r * NTOT_ + c];
      xio[(size_t)r * NTOT_ + c] = v;
      vout[j][qq] = v;
    }

  if (DOTS) {
    __syncthreads();
    float* xfl = (float*)&As[0];   // [64][64] f32 = 16 KB
    #pragma unroll
    for (int j = 0; j < 2; j++)
      #pragma unroll
      for (int qq = 0; qq < 4; qq++)
        xfl[(wm * 16 + lk * 4 + qq) * 64 + wn * 32 + j * 16 + lr] = vout[j][qq];
    __syncthreads();
    const int row = t >> 3, sub = t & 7;
    const int gr = m0 + row;
    const int headx = n0 >> 9;
    const int p = k & 1;
    float xv8[8]; float nrm = 0.f;
    #pragma unroll
    for (int e = 0; e < 8; e++) {
      xv8[e] = xfl[row * 64 + sub * 8 + e];
      nrm += xv8[e] * xv8[e];
    }
    nrm = red8(nrm);
    if (sub == 0) atomicAdd(&normbuf[(p * 512 + gr) * 4 + headx], nrm);
    for (int j = 0; j < k; j++) {
      const float* wr = &xw[((size_t)j * B_ + gr) * NTOT_ + n0 + sub * 8];
      float s = 0.f;
      #pragma unroll
      for (int e = 0; e < 8; e++) s += xv8[e] * wr[e];
      s = red8(s);
      if (sub == 0) atomicAdd(&dotbuf[((p * 7 + j) * 512 + gr) * 4 + headx], s);
    }
  }
}

// ---------------- fused acond + y@Dy + z-partial kernel ----------------
// grid (32 nt, 8 mt), 512 threads. Computes acond rows inline from dot/norm
// buffers + zh history + b_y (LN), then y = relu(acond@Dy)*x -> ytile,
// xw_{k-1} = x*invnorm (k in 1..6), z partial = ytile@E -> zparts[nt].
__global__ __launch_bounds__(512) void k_yz(
    const unsigned short* __restrict__ DyT, const unsigned short* __restrict__ ET,
    const float* __restrict__ x, const float* __restrict__ bybx,
    const float* __restrict__ zhg,
    const float* __restrict__ lna_g, const float* __restrict__ lna_b,
    const float* __restrict__ log_damp,
    float* __restrict__ xw, float* __restrict__ dotbuf, float* __restrict__ normbuf,
    float* __restrict__ zparts, int k)
{
  __shared__ __align__(16) unsigned short Abuf[4][4096];  // acond [kt][row*64+slot*8]
  __shared__ __align__(16) unsigned short Dys[4][4096];
  __shared__ __align__(16) unsigned short Es[256 * 64];
  __shared__ __align__(16) unsigned short ytile[4096];
  __shared__ float invn_s[64];
  const int t = threadIdx.x;
  const int lane = t & 63, w = t >> 6;
  const int lr = lane & 15, lk = lane >> 4;
  const int l3 = lane >> 3, cch = lane & 7;
  const int nt = blockIdx.x, mt = blockIdx.y;
  const int m0 = mt * 64, n0 = nt * 64;
  const int wm = w & 3, wn = w >> 2;
  const int qb = (k - 1) & 1, pz = k & 1;

  // ---- issue all staging (8 loads/thread): Dy 4 ktiles + E slice ----
  #pragma unroll
  for (int kt = 0; kt < 4; kt++) {
    int rr = w * 8 + l3;
    stage16(&DyT[(size_t)(n0 + rr) * 256 + kt * 64 + ((cch ^ (rr & 7)) << 3)],
            &Dys[kt][w * 512], lane);
  }
  #pragma unroll
  for (int p = 0; p < 4; p++) {
    int d = p * 64 + w * 8 + l3;
    stage16(&ET[(size_t)d * 2048 + n0 + ((cch ^ (d & 7)) << 3)],
            &Es[(p * 64 + w * 8) * 64], lane);
  }

  // ---- phase A: acond (redundant per nt, cheap) ----
  {
    const float lam = 1.f / (1.f + expf(-log_damp[0]));
    const int row = t >> 3, sub = t & 7;
    const int gr = m0 + row;
    const int head = sub >> 1;
    float a8[32];
    #pragma unroll
    for (int i = 0; i < 32; i++) a8[i] = 0.f;
    if (k >= 1) {
      float nb = normbuf[(qb * 512 + gr) * 4 + head];
      if (sub == 0) {
        float nx = normbuf[(qb * 512 + gr) * 4 + (n0 >> 9)];
        invn_s[row] = 1.f / (sqrtf(nx) + 1e-8f);
      }
      float lp = 1.f;
      for (int j = k - 1; j >= 0; j--) {
        float djv = (j == k - 1) ? nb / (sqrtf(nb) + 1e-8f)
                                 : dotbuf[((qb * 7 + j) * 512 + gr) * 4 + head];
        float cj = (1.f - lam) * lp * djv;
        const float* zr = zhg + ((size_t)j * B_ + gr) * D_ + sub * 32;
        #pragma unroll
        for (int i8 = 0; i8 < 8; i8++) {
          float4 zv = *(const float4*)(zr + i8 * 4);
          a8[i8 * 4 + 0] += cj * zv.x; a8[i8 * 4 + 1] += cj * zv.y;
          a8[i8 * 4 + 2] += cj * zv.z; a8[i8 * 4 + 3] += cj * zv.w;
        }
        lp *= lam;
      }
    }
    const float* byr = bybx + (size_t)gr * 512 + sub * 32;
    #pragma unroll
    for (int i8 = 0; i8 < 8; i8++) {
      float4 bv = *(const float4*)(byr + i8 * 4);
      a8[i8 * 4 + 0] += bv.x; a8[i8 * 4 + 1] += bv.y;
      a8[i8 * 4 + 2] += bv.z; a8[i8 * 4 + 3] += bv.w;
    }
    float s = 0.f;
    #pragma unroll
    for (int i = 0; i < 32; i++) s += a8[i];
    s = red8(s);
    float mu = s * (1.f / 256.f);
    float s2 = 0.f;
    #pragma unroll
    for (int i = 0; i < 32; i++) { float cc = a8[i] - mu; s2 += cc * cc; }
    s2 = red8(s2);
    float rin = rsqrtf(s2 * (1.f / 256.f) + 1e-5f);
    int kt = sub >> 1;
    #pragma unroll
    for (int cc4 = 0; cc4 < 4; cc4++) {
      int c64 = (sub & 1) * 4 + cc4;
      bf16x8 pk;
      #pragma unroll
      for (int e = 0; e < 8; e++) {
        int d = sub * 32 + cc4 * 8 + e;
        pk[e] = (short)f2b((a8[cc4 * 8 + e] - mu) * rin * lna_g[d] + lna_b[d]);
      }
      *(bf16x8*)&Abuf[kt][row * 64 + ((c64 ^ (row & 7)) << 3)] = pk;
    }
  }
  // zero parity buffers for this step's gemm_x (nt==0 blocks only; disjoint
  // from the parity read above)
  if (nt == 0) {
    for (int idx = t; idx < 7 * 64 * 4; idx += 512) {
      int j = idx >> 8, rem = idx & 255;
      dotbuf[((pz * 7 + j) * 512 + m0 + (rem >> 2)) * 4 + (rem & 3)] = 0.f;
    }
    if (t < 256) normbuf[(pz * 512 + m0 + (t >> 2)) * 4 + (t & 3)] = 0.f;
  }

  WAITV0;
  __syncthreads();

  // ---- phase B: y = relu(acond @ Dy) * x ----
  f32x4 yacc[2];
  yacc[0] = (f32x4){0.f, 0.f, 0.f, 0.f};
  yacc[1] = (f32x4){0.f, 0.f, 0.f, 0.f};
  #pragma unroll
  for (int kt = 0; kt < 4; kt++)
    #pragma unroll
    for (int ks = 0; ks < 2; ks++) {
      int q = ks * 4 + lk;
      int r = wm * 16 + lr;
      bf16x8 af = *(const bf16x8*)&Abuf[kt][r * 64 + ((q ^ (r & 7)) << 3)];
      #pragma unroll
      for (int j2 = 0; j2 < 2; j2++) {
        int c = wn * 32 + j2 * 16 + lr;
        bf16x8 bf = *(const bf16x8*)&Dys[kt][c * 64 + ((q ^ (c & 7)) << 3)];
        yacc[j2] = __builtin_amdgcn_mfma_f32_16x16x32_bf16(af, bf, yacc[j2], 0, 0, 0);
      }
    }
  const bool wxw = (k >= 1 && k < KSTEPS - 1);
  #pragma unroll
  for (int j2 = 0; j2 < 2; j2++)
    #pragma unroll
    for (int qq = 0; qq < 4; qq++) {
      int rl = wm * 16 + lk * 4 + qq;
      int cl = wn * 32 + j2 * 16 + lr;
      float xv = x[(size_t)(m0 + rl) * NTOT_ + n0 + cl];
      float v = fmaxf(yacc[j2][qq], 0.f) * xv;
      ytile[rl * 64 + ((((cl >> 3) ^ (rl & 7)) << 3) | (cl & 7))] = f2b(v);
      if (wxw)
        xw[((size_t)(k - 1) * B_ + m0 + rl) * NTOT_ + n0 + cl] = xv * invn_s[rl];
    }
  __syncthreads();

  // ---- phase C: z partial = ytile @ E ----
  f32x4 zacc[8];
  #pragma unroll
  for (int j = 0; j < 8; j++) zacc[j] = (f32x4){0.f, 0.f, 0.f, 0.f};
  #pragma unroll
  for (int ks = 0; ks < 2; ks++) {
    int q = ks * 4 + lk;
    int r = wm * 16 + lr;
    bf16x8 af = *(const bf16x8*)&ytile[r * 64 + ((q ^ (r & 7)) << 3)];
    #pragma unroll
    for (int j = 0; j < 8; j++) {
      int c = wn * 128 + j * 16 + lr;
      bf16x8 bf = *(const bf16x8*)&Es[c * 64 + ((q ^ (c & 7)) << 3)];
      zacc[j] = __builtin_amdgcn_mfma_f32_16x16x32_bf16(af, bf, zacc[j], 0, 0, 0);
    }
  }
  float* zp = zparts + (size_t)nt * (B_ * D_);
  #pragma unroll
  for (int j = 0; j < 8; j++)
    #pragma unroll
    for (int qq = 0; qq < 4; qq++) {
      int r = m0 + wm * 16 + lk * 4 + qq;
      int d = wn * 128 + j * 16 + lr;
      zp[(size_t)r * D_ + d] = zacc[j][qq];
    }
}

// ---------------- f32 tiled GEMM (encoder only) ----------------
template<int ACT>
__global__ __launch_bounds__(256) void gemm_tile(
    const float* __restrict__ A, const float* __restrict__ W,
    const float* __restrict__ bias, float* __restrict__ out,
    unsigned short* __restrict__ outb, int M, int N, int K, int kchunk)
{
  __shared__ float As[16][68];
  __shared__ float Bs[16][68];
  const int tid = threadIdx.x;
  const int row0 = blockIdx.y * 64;
  const int col0 = blockIdx.x * 64;
  const int k0 = blockIdx.z * kchunk;
  const int ty = tid >> 4, tx = tid & 15;
  const int ar = tid >> 4, ak = tid & 15;
  const int br = tid >> 6, bc = tid & 63;
  float acc[4][4] = {};
  for (int kk = k0; kk < k0 + kchunk; kk += 16) {
    #pragma unroll
    for (int i = 0; i < 4; i++) {
      int r = ar + i * 16;
      As[ak][r] = A[(size_t)(row0 + r) * K + kk + ak];
    }
    #pragma unroll
    for (int i = 0; i < 4; i++) {
      int kr = br + i * 4;
      Bs[kr][bc] = W[(size_t)(kk + kr) * N + col0 + bc];
    }
    __syncthreads();
    #pragma unroll
    for (int q = 0; q < 16; q++) {
      float4 av = *(const float4*)&As[q][ty * 4];
      float4 bv = *(const float4*)&Bs[q][tx * 4];
      float aa[4] = {av.x, av.y, av.z, av.w};
      float bb[4] = {bv.x, bv.y, bv.z, bv.w};
      #pragma unroll
      for (int i = 0; i < 4; i++)
        #pragma unroll
        for (int j = 0; j < 4; j++)
          acc[i][j] = fmaf(aa[i], bb[j], acc[i][j]);
    }
    __syncthreads();
  }
  const bool parts = (gridDim.z > 1);
  float* o = out + (parts ? (size_t)blockIdx.z * (size_t)M * N : (size_t)0);
  #pragma unroll
  for (int i = 0; i < 4; i++) {
    int r = row0 + ty * 4 + i;
    #pragma unroll
    for (int j = 0; j < 4; j++) {
      int c = col0 + tx * 4 + j;
      float v = acc[i][j];
      if (!parts) {
        if (bias) v += bias[c];
        if (ACT == 2) v = gelu_exact(v);
      }
      o[(size_t)r * N + c] = v;
      if (!parts && outb) outb[(size_t)r * N + c] = f2b(v);
    }
  }
}

// ---------------- weight prep ----------------
__global__ __launch_bounds__(256) void k_prep(
    const float* __restrict__ D_y, const float* __restrict__ D_x,
    const float* __restrict__ xinit_w, const float* __restrict__ E,
    const float* __restrict__ By_w, const float* __restrict__ Bx_w,
    unsigned short* __restrict__ DyT, unsigned short* __restrict__ DxT,
    unsigned short* __restrict__ xinitT, unsigned short* __restrict__ ET,
    float* __restrict__ Wcat)
{
  const int t = threadIdx.x;
  if (blockIdx.y == 4) {
    if (blockIdx.x >= 32) return;
    int k0 = ((int)blockIdx.x >> 3) * 64, n0 = ((int)blockIdx.x & 7) * 64;
    for (int i = 0; i < 16; i++) {
      int local = i * 256 + t;
      int kk = local >> 6, nn = local & 63;
      int n = n0 + nn;
      float v = (n < 256) ? By_w[(size_t)(k0 + kk) * 256 + n]
                          : Bx_w[(size_t)(k0 + kk) * 256 + (n - 256)];
      Wcat[(size_t)(k0 + kk) * 512 + n] = v;
    }
    return;
  }
  __shared__ float T[64][65];
  const float* in; unsigned short* out; int Kd, Nd, head, nx;
  switch (blockIdx.y) {
    case 0:  in = D_y;     out = DyT;    Kd = 256;  Nd = 2048; head = 1; nx = 32; break;
    case 1:  in = D_x;     out = DxT;    Kd = 256;  Nd = 2048; head = 1; nx = 32; break;
    case 2:  in = xinit_w; out = xinitT; Kd = 256;  Nd = 2048; head = 0; nx = 32; break;
    default: in = E;       out = ET;     Kd = 2048; Nd = 256;  head = 0; nx = 4;  break;
  }
  const int n0 = ((int)blockIdx.x % nx) * 64, k0 = ((int)blockIdx.x / nx) * 64;
  const int tx = t & 63, ty = t >> 6;
  #pragma unroll
  for (int i = 0; i < 16; i++) {
    int k = k0 + ty + i * 4;
    int n = n0 + tx;
    float v;
    if (head) v = in[((size_t)(n >> 9) * 256 + k) * 512 + (n & 511)];
    else      v = in[(size_t)k * Nd + n];
    T[ty + i * 4][tx] = v;
  }
  __syncthreads();
  #pragma unroll
  for (int i = 0; i < 16; i++) {
    int n = n0 + ty + i * 4;
    out[(size_t)n * Kd + k0 + tx] = f2b(T[tx][ty + i * 4]);
  }
}

// ---------------- encoder LN ----------------
__global__ __launch_bounds__(256) void k_ln_enc(
    const float* __restrict__ in, int nparts, int stride,
    const float* __restrict__ pre_bias,
    const float* __restrict__ g, const float* __restrict__ bta,
    float* __restrict__ out)
{
  __shared__ float red[256];
  int b = blockIdx.x, d = threadIdx.x;
  float v = 0.f;
  for (int p = 0; p < nparts; p++) v += in[(size_t)p * stride + (size_t)b * 256 + d];
  v = gelu_exact(v + pre_bias[d]);
  float mu = blockReduceSum256(v, red) * (1.f / 256.f);
  float c = v - mu;
  float var = blockReduceSum256(c * c, red) * (1.f / 256.f);
  out[(size_t)b * 256 + d] = c * rsqrtf(var + 1e-5f) * g[d] + bta[d];
}

// ---------------- z-LN (+ optional fused value head) ----------------
template<int VAL>
__global__ __launch_bounds__(256) void k_ln_z(
    const float* __restrict__ zparts, const float* __restrict__ bybx,
    const float* __restrict__ lnz_g, const float* __restrict__ lnz_b,
    float* __restrict__ zh_k, unsigned short* __restrict__ zbx_bf,
    const float* __restrict__ w1, const float* __restrict__ b1,
    const float* __restrict__ w2, const float* __restrict__ b2,
    float* __restrict__ vout)
{
  __shared__ float red[256];
  __shared__ float zn[256];
  int b = blockIdx.x, d = threadIdx.x;
  float v = 0.f;
  #pragma unroll
  for (int p = 0; p < 32; p++) v += zparts[(size_t)p * (B_ * D_) + (size_t)b * D_ + d];
  float mu = blockReduceSum256(v, red) * (1.f / 256.f);
  float c = v - mu;
  float var = blockReduceSum256(c * c, red) * (1.f / 256.f);
  float vn = c * rsqrtf(var + 1e-5f) * lnz_g[d] + lnz_b[d];
  zh_k[(size_t)b * D_ + d] = vn;
  zbx_bf[(size_t)b * D_ + d] = f2b(vn + bybx[(size_t)b * 512 + 256 + d]);
  if (VAL) {
    zn[d] = vn; __syncthreads();
    int j = d & 127, ih = d >> 7;
    float s = 0.f;
    #pragma unroll 4
    for (int i = ih * 128; i < ih * 128 + 128; i++) s += zn[i] * w1[(size_t)i * 128 + j];
    red[d] = s; __syncthreads();
    if (d < 128) red[d] = gelu_exact(red[d] + red[d + 128] + b1[j]) * w2[d];
    __syncthreads();
    #pragma unroll
    for (int st = 64; st > 0; st >>= 1) {
      if (d < st) red[d] += red[d + st];
      __syncthreads();
    }
    if (d == 0) vout[b] = tanhf(red[0] + b2[0]);
  }
}

extern "C" void kernel_launch(void* const* d_in, const int* in_sizes, int n_in,
                              void* d_out, int out_size, void* d_ws, size_t ws_size,
                              hipStream_t stream) {
  const float* boards   = (const float*)d_in[0];
  const float* enc_w1   = (const float*)d_in[1];
  const float* enc_b1   = (const float*)d_in[2];
  const float* enc_ln_g = (const float*)d_in[3];
  const float* enc_ln_b = (const float*)d_in[4];
  const float* enc_w2   = (const float*)d_in[5];
  const float* enc_b2   = (const float*)d_in[6];
  const float* xinit_w  = (const float*)d_in[7];
  const float* xinit_b  = (const float*)d_in[8];
  const float* D_y      = (const float*)d_in[9];
  const float* E        = (const float*)d_in[10];
  const float* D_x      = (const float*)d_in[11];
  const float* By_w     = (const float*)d_in[12];
  const float* Bx_w     = (const float*)d_in[13];
  const float* lna_g    = (const float*)d_in[14];
  const float* lna_b    = (const float*)d_in[15];
  const float* lnz_g    = (const float*)d_in[16];
  const float* lnz_b    = (const float*)d_in[17];
  const float* log_damp = (const float*)d_in[18];
  const float* vh_w1    = (const float*)d_in[19];
  const float* vh_b1    = (const float*)d_in[20];
  const float* vh_w2    = (const float*)d_in[21];
  const float* vh_b2    = (const float*)d_in[22];
  float* outp = (float*)d_out;

  float* ws = (float*)d_ws;
  size_t o = 0;
  float* x      = ws + o; o += (size_t)B_ * NTOT_;
  float* xw     = ws + o; o += (size_t)7 * B_ * NTOT_;
  float* zh     = ws + o; o += (size_t)KSTEPS * B_ * D_;
  float* hparts = ws + o; o += (size_t)8 * B_ * D_;
  float* h      = ws + o; o += (size_t)B_ * D_;
  float* bvec   = ws + o; o += (size_t)B_ * D_;
  float* bybx   = ws + o; o += (size_t)B_ * 512;
  float* Wcat   = ws + o; o += (size_t)256 * 512;
  float* zparts = ws + o; o += (size_t)32 * B_ * D_;
  float* dotbuf = ws + o; o += (size_t)2 * 7 * 512 * 4;
  float* normbuf= ws + o; o += (size_t)2 * 512 * 4;
  unsigned short* DyT     = (unsigned short*)(ws + o); o += (size_t)NTOT_ * D_ / 2;
  unsigned short* DxT     = (unsigned short*)(ws + o); o += (size_t)NTOT_ * D_ / 2;
  unsigned short* ET      = (unsigned short*)(ws + o); o += (size_t)D_ * NTOT_ / 2;
  unsigned short* xinitT  = (unsigned short*)(ws + o); o += (size_t)NTOT_ * D_ / 2;
  unsigned short* bvec_bf = (unsigned short*)(ws + o); o += (size_t)B_ * D_ / 2;
  unsigned short* zbx_bf  = (unsigned short*)(ws + o); o += (size_t)B_ * D_ / 2;

  // ---- one-time weight prep ----
  k_prep<<<dim3(128, 5), 256, 0, stream>>>(D_y, D_x, xinit_w, E, By_w, Bx_w,
                                           DyT, DxT, xinitT, ET, Wcat);
  // ---- encoder (f32) ----
  gemm_tile<0><<<dim3(4, 8, 8), 256, 0, stream>>>(boards, enc_w1, nullptr, hparts,
                                                  nullptr, B_, D_, 768, 96);
  k_ln_enc<<<B_, 256, 0, stream>>>(hparts, 8, B_ * D_, enc_b1, enc_ln_g, enc_ln_b, h);
  gemm_tile<0><<<dim3(4, 8, 1), 256, 0, stream>>>(h, enc_w2, enc_b2, bvec, bvec_bf,
                                                  B_, D_, D_, D_);
  gemm_tile<0><<<dim3(8, 8, 1), 256, 0, stream>>>(bvec, Wcat, nullptr, bybx, nullptr,
                                                  B_, 512, D_, D_);
  // x0 = relu(bvec @ xinit_w + bias)  (no dots phase)
  k_gemm_x<0, 0><<<dim3(32, 8), 512, 0, stream>>>(bvec_bf, xinitT, xinit_b, x,
                                                  nullptr, nullptr, nullptr, 0);

  // ---- K thinking steps ----
  for (int k = 0; k < KSTEPS; k++) {
    k_yz<<<dim3(32, 8), 512, 0, stream>>>(DyT, ET, x, bybx, zh,
                                          lna_g, lna_b, log_damp,
                                          xw, dotbuf, normbuf, zparts, k);
    if (k < KSTEPS - 1) {
      k_ln_z<0><<<B_, 256, 0, stream>>>(zparts, bybx, lnz_g, lnz_b,
                                        zh + (size_t)k * B_ * D_, zbx_bf,
                                        nullptr, nullptr, nullptr, nullptr, nullptr);
      k_gemm_x<1, 1><<<dim3(32, 8), 512, 0, stream>>>(zbx_bf, DxT, nullptr, x,
                                                      xw, dotbuf, normbuf, k);
    } else {
      k_ln_z<1><<<B_, 256, 0, stream>>>(zparts, bybx, lnz_g, lnz_b,
                                        zh + (size_t)k * B_ * D_, zbx_bf,
                                        vh_w1, vh_b1, vh_w2, vh_b2, outp);
    }
  }
}